// Round 5
// baseline (97.512 us; speedup 1.0000x reference)
//
#include <hip/hip_runtime.h>

// AdderNet 2D: out[n,f,h,w] = -sum_{c,kh,kw} |W[f,c,kh,kw] - xpad[n,c,h+kh,w+kw]|
// x: (16,64,14,14) fp32, W: (64,64,3,3) fp32, out: (16,64,14,14) fp32
//
// R5: row-half split for occupancy. Grid = (fg=16, n=16, h=2) = 512 blocks,
// 1024 thr = 8 channel-classes (8 ch) x 128 px-lanes (98 active).
// LDS tile: 10 padded rows x 16 cols x 68 (ch-contiguous, conflict-free
// b128) = 43.5 KB -> 2 blocks/CU if VGPR<=64 (__launch_bounds__(1024,8)).
// W per thread: 288 dwords in 2 g-chunks of 144 (vs 576 in R4) -> less
// lgkmcnt-exposed s_load; 8 waves/SIMD hide the rest.

#define N_ 16
#define C_ 64
#define F_ 64
#define P_ 196
#define CPAD 68
#define ROWS 10
#define POS (ROWS * 16)   // 160 padded positions

__global__ __launch_bounds__(1024, 8) void adder2d_kernel(
    const float* __restrict__ x, const float* __restrict__ w,
    float* __restrict__ out)
{
    __shared__ __align__(16) float xt[POS * CPAD];   // 43,520 B

    const int tid = threadIdx.x;     // 0..1023
    const int fg  = blockIdx.x;      // 0..15 -> filters fg*4..fg*4+3
    const int n   = blockIdx.y;      // 0..15
    const int hh  = blockIdx.z;      // 0..1  output rows hh*7 .. hh*7+6

    // ---- zero tile (covers halo): 2720 float4 ----
    float4* xt4 = (float4*)xt;
    #pragma unroll
    for (int i = 0; i < 3; ++i) {
        int idx = tid + i * 1024;
        if (idx < POS * CPAD / 4) xt4[idx] = make_float4(0.f, 0.f, 0.f, 0.f);
    }
    __syncthreads();

    // ---- stage interior: lane = channel -> LDS store addr = pos*68 + c
    //      (stride-1 across lanes, conflict-free). Tile covers padded rows
    //      [6*hh, 6*hh+10); input row ir = 6*hh + rl - 1, valid 0..13.
    {
        const int c  = tid & 63;
        const int ph = tid >> 6;     // 0..15
        const float* xc = x + (n * C_ + c) * P_;
        #pragma unroll
        for (int i = 0; i < 9; ++i) {
            const int e = ph + 16 * i;        // local (row,col) index, 10x14
            if (e < 140) {
                const int rl  = e / 14;
                const int col = e - rl * 14;
                const int ir  = 6 * hh + rl - 1;
                if (ir >= 0 && ir <= 13)
                    xt[(rl * 16 + col + 1) * CPAD + c] = xc[ir * 14 + col];
            }
        }
    }
    __syncthreads();

    // ---- compute: class cq (8 ch) x px-lane; 4 filters serial ----
    const int cq  = __builtin_amdgcn_readfirstlane(tid >> 7);  // 0..7, wave-uniform
    const int pxl = tid & 127;                                 // 0..127, 98 active
    float a0 = 0.f, a1 = 0.f, a2 = 0.f, a3 = 0.f;

    if (pxl < 98) {
        const int rr  = pxl / 14;            // 0..6
        const int col = pxl - rr * 14;       // 0..13
        // window top-left in tile: local row = hh + rr, padded col = col
        const float* base = xt + ((hh + rr) * 16 + col) * CPAD + cq * 8;
        const int fbase = fg * 4;

        #pragma unroll 1
        for (int g = 0; g < 2; ++g) {        // two 4-channel groups
            float4 xv[9];
            #pragma unroll
            for (int kh = 0; kh < 3; ++kh)
                #pragma unroll
                for (int kw = 0; kw < 3; ++kw)
                    xv[kh * 3 + kw] =
                        *(const float4*)(base + g * 4 + (kh * 16 + kw) * CPAD);

            #pragma unroll
            for (int f = 0; f < 4; ++f) {
                const float* wf = w + (fbase + f) * (C_ * 9) + (cq * 8 + g * 4) * 9;
                float a = 0.f;
                #pragma unroll
                for (int kk = 0; kk < 9; ++kk) {
                    a += fabsf(wf[0 * 9 + kk] - xv[kk].x)
                       + fabsf(wf[1 * 9 + kk] - xv[kk].y)
                       + fabsf(wf[2 * 9 + kk] - xv[kk].z)
                       + fabsf(wf[3 * 9 + kk] - xv[kk].w);
                }
                if (f == 0) a0 += a;
                else if (f == 1) a1 += a;
                else if (f == 2) a2 += a;
                else a3 += a;
            }
        }
    }

    // ---- 8-way class reduce through LDS (reuse xt) ----
    __syncthreads();
    ((float4*)xt)[cq * 128 + pxl] = make_float4(a0, a1, a2, a3);
    __syncthreads();

    if (tid < 98) {
        float4 t = make_float4(0.f, 0.f, 0.f, 0.f);
        #pragma unroll
        for (int j = 0; j < 8; ++j) {
            float4 r = ((float4*)xt)[j * 128 + tid];
            t.x += r.x; t.y += r.y; t.z += r.z; t.w += r.w;
        }
        const int rr  = tid / 14;
        const int col = tid - rr * 14;
        const int ro  = 7 * hh + rr;
        float* op = out + (n * F_ + fg * 4) * P_ + ro * 14 + col;
        op[0 * P_] = -t.x;
        op[1 * P_] = -t.y;
        op[2 * P_] = -t.z;
        op[3 * P_] = -t.w;
    }
}

extern "C" void kernel_launch(void* const* d_in, const int* in_sizes, int n_in,
                              void* d_out, int out_size, void* d_ws, size_t ws_size,
                              hipStream_t stream) {
    const float* x = (const float*)d_in[0];
    const float* w = (const float*)d_in[1];
    float* out = (float*)d_out;
    dim3 grid(F_ / 4, N_, 2);
    adder2d_kernel<<<grid, 1024, 0, stream>>>(x, w, out);
}

// Round 6
// 70.645 us; speedup vs baseline: 1.3803x; 1.3803x over previous
//
#include <hip/hip_runtime.h>

// AdderNet 2D: out[n,f,h,w] = -sum_{c,kh,kw} |W[f,c,kh,kw] - xpad[n,c,h+kh,w+kw]|
// x: (16,64,14,14) fp32, W: (64,64,3,3) fp32, out: (16,64,14,14) fp32
//
// R6: lane = f. x reads are lane-uniform (L1 broadcast, NO LDS staging);
// W[f][4ch][9] = 36 contiguous floats per lane, loaded ONCE into VGPRs
// (9 dwordx4). Wave = (n, row, ch-quad): 14 pixel accumulators in regs,
// hot loop is pure VALU (no ds_read, no s_load of W, no barriers).
// Block = 1024 thr = 16 waves = all 64 channels -> single LDS reduce
// (stride 15 -> conflict-free), no atomics. Grid = 14 rows x 16 n.

#define N_ 16
#define C_ 64
#define F_ 64
#define P_ 196

__global__ __launch_bounds__(1024) void adder2d_kernel(
    const float* __restrict__ x, const float* __restrict__ w,
    float* __restrict__ out)
{
    __shared__ float part[16][64 * 15];   // [ch-quad][f*15 + px], 61,440 B

    const int tid = threadIdx.x;          // 0..1023
    const int row = blockIdx.x;           // 0..13 output row
    const int n   = blockIdx.y;           // 0..15
    const int f   = tid & 63;             // lane = filter
    const int cgq = __builtin_amdgcn_readfirstlane(tid >> 6);  // 0..15
    const int cbase = cgq * 4;            // 4 channels per wave

    // ---- W[f][cbase..cbase+3][0..8]: 36 contiguous floats, 16B-aligned ----
    float Wr[36];
    {
        const float4* wp = (const float4*)(w + f * (C_ * 9) + cbase * 9);
        #pragma unroll
        for (int i = 0; i < 9; ++i) {
            float4 t = wp[i];
            Wr[4 * i + 0] = t.x; Wr[4 * i + 1] = t.y;
            Wr[4 * i + 2] = t.z; Wr[4 * i + 3] = t.w;
        }
    }

    float acc[14];
    #pragma unroll
    for (int p = 0; p < 14; ++p) acc[p] = 0.f;

    // ---- hot loop: 4 channels x 3 kh rows; x row is lane-uniform ----
    #pragma unroll
    for (int cl = 0; cl < 4; ++cl) {
        const float* xc = x + (n * C_ + (cbase + cl)) * P_;
        #pragma unroll
        for (int kh = 0; kh < 3; ++kh) {
            const int ir = row + kh - 1;          // input row, -1..14
            float xr[16];                          // padded row in regs
            xr[0] = 0.f; xr[15] = 0.f;
            if (ir >= 0 && ir <= 13) {             // block-uniform branch
                #pragma unroll
                for (int j = 0; j < 14; ++j) xr[j + 1] = xc[ir * 14 + j];
            } else {
                #pragma unroll
                for (int j = 0; j < 14; ++j) xr[j + 1] = 0.f;
            }
            #pragma unroll
            for (int kw = 0; kw < 3; ++kw) {
                const float wv = Wr[cl * 9 + kh * 3 + kw];
                #pragma unroll
                for (int p = 0; p < 14; ++p)
                    acc[p] += fabsf(wv - xr[p + kw]);
            }
        }
    }

    // ---- partials -> LDS (stride 15: gcd(15,32)=1 -> <=2-way = free) ----
    #pragma unroll
    for (int p = 0; p < 14; ++p) part[cgq][f * 15 + p] = acc[p];
    __syncthreads();

    // ---- 16-way channel reduce + store (896 outputs this block) ----
    if (tid < 896) {
        const int ff = tid / 14;
        const int px = tid - ff * 14;
        float s = 0.f;
        #pragma unroll
        for (int q = 0; q < 16; ++q) s += part[q][ff * 15 + px];
        out[(n * F_ + ff) * P_ + row * 14 + px] = -s;
    }
}

extern "C" void kernel_launch(void* const* d_in, const int* in_sizes, int n_in,
                              void* d_out, int out_size, void* d_ws, size_t ws_size,
                              hipStream_t stream) {
    const float* x = (const float*)d_in[0];
    const float* w = (const float*)d_in[1];
    float* out = (float*)d_out;
    dim3 grid(14, N_);
    adder2d_kernel<<<grid, 1024, 0, stream>>>(x, w, out);
}